// Round 10
// baseline (87.135 us; speedup 1.0000x reference)
//
#include <hip/hip_runtime.h>

// ContextVector additive-attention (Bahdanau) — round 10.
// Model (established R8/R9): kernel is VALU-throughput-bound; v_pk_*_f32 is
// half-rate (FP32 peak 157TF = 2 FLOP/lane/cyc) so packing saves registers,
// not cycles. R10 = R8 base with:
//  (1) d = pk_fma(ea, eb_dup, 1) fusion (R8's proven duplicated-pair LDS
//      layout; NO op_sel): 18pk+4rcp -> 14pk+4rcp per 8 elems.
//  (2) 1024 blocks x 512 thr, block=(b, 2 s): 4 blocks/CU load balance.
//  (3) prep split finer (R7 geometry, numerics proven): 1024 blocks.

constexpr int B  = 8;
constexpr int TE = 512;   // T_enc
constexpr int DE = 256;   // D_enc
constexpr int TD = 256;   // T_dec
constexpr int DD = 512;   // D_dec

constexpr float LOG2E  = 1.4426950408889634f;
constexpr float K2     = 2.8853900817779268f;   // 2*log2(e): exp2(K2*z) = e^{2z}
constexpr float ACLAMP = 10.0f;                 // pair products can't overflow

typedef float f2 __attribute__((ext_vector_type(2)));

__device__ __forceinline__ float fexp2(float x){ return __builtin_amdgcn_exp2f(x); }
__device__ __forceinline__ float frcp (float x){ return __builtin_amdgcn_rcpf(x); }
__device__ __forceinline__ f2 pk_mul(f2 a, f2 b){ f2 d; asm("v_pk_mul_f32 %0, %1, %2":"=v"(d):"v"(a),"v"(b)); return d; }
__device__ __forceinline__ f2 pk_fma(f2 a, f2 b, f2 c){ f2 d; asm("v_pk_fma_f32 %0, %1, %2, %3":"=v"(d):"v"(a),"v"(b),"v"(c)); return d; }

__device__ __forceinline__ float e2z(float z){   // e^{2z}, clamped
  return fexp2(K2 * fminf(fmaxf(z, -ACLAMP), ACLAMP));
}

// Prep: bid<512: encE[b][e][t] = e^{2*(enc@Wenc)}, transposed store, 8 t-rows/blk
//       bid>=512: decE[b*TD+s][e] = e^{2*(dec@Wdec)}, row-major, 4 s-rows/blk
// (R7 geometry — numerics identical to R8's proven prep, finer block split.)
__global__ __launch_bounds__(256)
void prep_kernel(const float* __restrict__ enc, const float* __restrict__ Wenc,
                 const float* __restrict__ dec, const float* __restrict__ Wdec,
                 float* __restrict__ encE, float* __restrict__ decE)
{
  __shared__ __align__(16) float LT[8][260];
  const int tid = threadIdx.x;
  const int bid = blockIdx.x;
  if (bid < 512){
    const int r0 = bid*8;                  // global row = b*TE + t
    const int b = r0 >> 9, t0 = r0 & (TE-1);
    const int col = tid;
    float acc[8];
    #pragma unroll
    for (int r=0;r<8;r++) acc[r]=0.f;
    const float* Arow = enc + (size_t)r0*DE;
    const float* wp   = Wenc + col;
    for (int k4=0;k4<DE/4;k4++){
      const float w0 = wp[(size_t)(4*k4  )*DE];   // coalesced over lanes
      const float w1 = wp[(size_t)(4*k4+1)*DE];
      const float w2 = wp[(size_t)(4*k4+2)*DE];
      const float w3 = wp[(size_t)(4*k4+3)*DE];
      #pragma unroll
      for (int r=0;r<8;r++){
        const float4 av = *(const float4*)(Arow + (size_t)r*DE + 4*k4); // uniform
        acc[r] += av.x*w0 + av.y*w1 + av.z*w2 + av.w*w3;
      }
    }
    #pragma unroll
    for (int r=0;r<8;r++) LT[r][col] = e2z(acc[r]);
    __syncthreads();
    // store: lane pair (le, jj) writes 16B contiguous per e-row
    const int wv = tid>>6, lane = tid&63, le = lane>>1, jj = lane&1;
    #pragma unroll
    for (int p=0;p<2;p++){
      const int e = p*128 + wv*32 + le;
      float4 val;
      val.x = LT[4*jj+0][e]; val.y = LT[4*jj+1][e];
      val.z = LT[4*jj+2][e]; val.w = LT[4*jj+3][e];
      *(float4*)(encE + (size_t)(b*DE + e)*TE + t0 + 4*jj) = val;
    }
  } else {
    const int r0 = (bid-512)*4;            // global row = b*TD + s
    const int col = tid;
    float acc[4];
    #pragma unroll
    for (int r=0;r<4;r++) acc[r]=0.f;
    const float* Arow = dec + (size_t)r0*DD;
    const float* wp   = Wdec + col;
    for (int k4=0;k4<DD/4;k4++){
      const float w0 = wp[(size_t)(4*k4  )*DE];
      const float w1 = wp[(size_t)(4*k4+1)*DE];
      const float w2 = wp[(size_t)(4*k4+2)*DE];
      const float w3 = wp[(size_t)(4*k4+3)*DE];
      #pragma unroll
      for (int r=0;r<4;r++){
        const float4 av = *(const float4*)(Arow + (size_t)r*DD + 4*k4); // uniform
        acc[r] += av.x*w0 + av.y*w1 + av.z*w2 + av.w*w3;
      }
    }
    #pragma unroll
    for (int r=0;r<4;r++)
      decE[(size_t)(r0+r)*DE + col] = e2z(acc[r]);   // coalesced
  }
}

// Main: block = (b, 2 decoder steps). 1024 blocks x 512 threads (8 waves).
// phase1: logit'[s][t] = sum_e vn_e * rcp(1 + Ea[e][t]*Eb[s][e])   (log2 domain)
// phase2: weights = 2^logit' / sum (no max-subtract: |logit'| <= ~40)
// phase3: context = weights @ enc
template<bool USE_DWT>
__global__ __launch_bounds__(512, 8)
void attn_kernel(const float* __restrict__ enc, const float* __restrict__ dec,
                 const float* __restrict__ Wdec, const float* __restrict__ v,
                 const float* __restrict__ encE, const float* __restrict__ decE,
                 float* __restrict__ outCtx, float* __restrict__ outW)
{
  __shared__ __align__(16) float ebp[DE*4];     // 4 KB {eb_s0,eb_s0,eb_s1,eb_s1} per e
  __shared__ __align__(16) float vnp[DE*2];     // 2 KB {vn,vn} pairs
  __shared__ __align__(16) float part[8*TE];    // 16 KB [g*2+s][t]; reused ph3
  __shared__ __align__(16) float pl[2*TE];      // 4 KB exp values
  __shared__ float wsum[8], rs[2];

  const int tid = threadIdx.x;
  const int bid = ((blockIdx.x & 7) << 7) | (blockIdx.x >> 3);  // XCD-bijective
  const int b   = bid >> 7;
  const int sp0 = (bid & 127)*2;

  if (USE_DWT){
    if (tid < DE){
      const float* dp = decE + (size_t)(b*TD + sp0)*DE + tid;
      const float g0 = dp[0], g1 = dp[DE];
      float4 q; q.x = g0; q.y = g0; q.z = g1; q.w = g1;
      *(float4*)&ebp[tid*4] = q;
      const float vnv = -2.f*LOG2E*v[tid];
      *(f2*)&vnp[tid*2] = f2{vnv, vnv};
    }
    __syncthreads();
  } else {
    {  // stage 2 dec rows (1024 floats) into part
      const float* src = dec + (size_t)(b*TD + sp0)*DD;
      part[tid] = src[tid];
      part[tid + 512] = src[tid + 512];
    }
    __syncthreads();
    const int s = tid >> 8, e = tid & 255;     // 512 threads = 2 s x 256 e
    float a = 0.f;
    const float* wp  = Wdec + e;
    const float* dsp = part + s*DD;            // uniform per wave
    #pragma unroll 2
    for (int k4=0;k4<DD/4;k4++){
      const float4 qd = *(const float4*)(dsp + 4*k4);
      a += qd.x*wp[(size_t)(4*k4  )*DE] + qd.y*wp[(size_t)(4*k4+1)*DE]
         + qd.z*wp[(size_t)(4*k4+2)*DE] + qd.w*wp[(size_t)(4*k4+3)*DE];
    }
    const float eb = e2z(a);
    __syncthreads();                           // part re-used below
    *(f2*)&ebp[e*4 + 2*s] = f2{eb, eb};
    if (s == 0) *(f2*)&vnp[e*2] = f2{-2.f*LOG2E*v[e], -2.f*LOG2E*v[e]};
    __syncthreads();
  }

  // ---- phase 1: thread (g = e-quarter, q = t-quad). 64 e x 2 s x 4 t ----
  // Per e-iter: 1 coalesced b128 (ea), 1 uniform b128 (eb pairs), 1 uniform
  // b64 (vn pair); 14 pk + 4 rcp for 8 elements.
  {
    const int g = tid >> 7, q = tid & 127;
    f2 acc0L = f2{0.f,0.f}, acc0H = f2{0.f,0.f};
    f2 acc1L = f2{0.f,0.f}, acc1H = f2{0.f,0.f};
    const f2 one2 = {1.f, 1.f};
    const float* xp = encE + (size_t)(b*DE + 64*g)*TE + 4*q;
    const float* ep = ebp + 64*g*4;
    const float* np = vnp + 64*g*2;
    #pragma unroll 2
    for (int i=0;i<64;i++){
      const float4 ea = *(const float4*)(xp + (size_t)i*TE);  // coalesced b128
      const float4 eb = *(const float4*)(ep + i*4);   // uniform b128 {s0s0 s1s1}
      const f2 vn2    = *(const f2*)(np + i*2);       // uniform b64 {vn,vn}
      const f2 taL = {ea.x, ea.y}, taH = {ea.z, ea.w};
      const f2 d0L = pk_fma(taL, f2{eb.x, eb.y}, one2);
      const f2 d0H = pk_fma(taH, f2{eb.x, eb.y}, one2);
      const f2 d1L = pk_fma(taL, f2{eb.z, eb.w}, one2);
      const f2 d1H = pk_fma(taH, f2{eb.z, eb.w}, one2);
      const f2 DL = pk_mul(d0L, d1L);                 // < 2^115.6 always
      const f2 DH = pk_mul(d0H, d1H);
      const f2 RL = {frcp(DL.x), frcp(DL.y)};
      const f2 RH = {frcp(DH.x), frcp(DH.y)};
      acc0L = pk_fma(vn2, pk_mul(RL, d1L), acc0L);
      acc0H = pk_fma(vn2, pk_mul(RH, d1H), acc0H);
      acc1L = pk_fma(vn2, pk_mul(RL, d0L), acc1L);
      acc1H = pk_fma(vn2, pk_mul(RH, d0H), acc1H);
    }
    float4 st0; st0.x=acc0L.x; st0.y=acc0L.y; st0.z=acc0H.x; st0.w=acc0H.y;
    float4 st1; st1.x=acc1L.x; st1.y=acc1L.y; st1.z=acc1H.x; st1.w=acc1H.y;
    *(float4*)&part[(g*2 + 0)*TE + 4*q] = st0;
    *(float4*)&part[(g*2 + 1)*TE + 4*q] = st1;
  }
  __syncthreads();

  // ---- phase 2: wave w: s = w>>2 (0..1), chunk c = w&3 (128 t each) ----
  {
    const int w = tid >> 6, lane = tid & 63;
    const int s = w >> 2, c = w & 3;
    const int t0 = c*128 + 2*lane;
    f2 a = f2{0.f,0.f};
    #pragma unroll
    for (int g=0; g<4; g++){
      const f2 p = *(const f2*)&part[(g*2 + s)*TE + t0];
      a.x += p.x; a.y += p.y;
    }
    f2 ex; ex.x = fexp2(a.x); ex.y = fexp2(a.y);
    *(f2*)&pl[s*TE + t0] = ex;                 // published BEFORE wsum barrier
    float sum = ex.x + ex.y;
    #pragma unroll
    for (int off=32; off>=1; off>>=1) sum += __shfl_xor(sum, off);
    if (lane==0) wsum[w] = sum;
    __syncthreads();
    const float S = wsum[s*4] + wsum[s*4+1] + wsum[s*4+2] + wsum[s*4+3];
    const float r = 1.0f / S;
    f2 wo; wo.x = ex.x*r; wo.y = ex.y*r;
    *(f2*)(outW + (size_t)(b*TD + sp0 + s)*TE + t0) = wo;
    if (lane==0 && c==0) rs[s] = r;
  }
  // (part fully consumed before the wsum barrier; pl published before it)

  // ---- phase 3: context. thread (h = t-half, e). 256 t x 2 s each ----
  {
    const int h = tid >> 8, e = tid & 255;
    float c0=0.f, c1=0.f;
    const float* encB = enc + (size_t)(b*TE + 256*h)*DE + e;
    const float* pb = pl + 256*h;
    #pragma unroll 2
    for (int t4=0;t4<64;t4++){
      const float4 q0 = *(const float4*)(pb + 0*TE + 4*t4);   // uniform b128
      const float4 q1 = *(const float4*)(pb + 1*TE + 4*t4);
      const float f0 = encB[(size_t)(4*t4  )*DE];             // coalesced
      const float f1 = encB[(size_t)(4*t4+1)*DE];
      const float f2_ = encB[(size_t)(4*t4+2)*DE];
      const float f3 = encB[(size_t)(4*t4+3)*DE];
      c0 += q0.x*f0+q0.y*f1+q0.z*f2_+q0.w*f3;
      c1 += q1.x*f0+q1.y*f1+q1.z*f2_+q1.w*f3;
    }
    float* partc = part;            // rows [h*2+s][e], 4 x 256
    partc[(h*2+0)*DE + e] = c0;
    partc[(h*2+1)*DE + e] = c1;
  }
  __syncthreads();
  {
    const int sp = tid >> 8, e = tid & 255;    // all 512 threads
    const float val = (part[(0*2+sp)*DE + e] + part[(1*2+sp)*DE + e]) * rs[sp];
    outCtx[(size_t)(b*TD + sp0 + sp)*DE + e] = val;
  }
}

extern "C" void kernel_launch(void* const* d_in, const int* in_sizes, int n_in,
                              void* d_out, int out_size, void* d_ws, size_t ws_size,
                              hipStream_t stream)
{
  const float* enc  = (const float*)d_in[0];
  const float* dec  = (const float*)d_in[1];
  const float* Wenc = (const float*)d_in[2];
  const float* Wdec = (const float*)d_in[3];
  const float* v    = (const float*)d_in[4];
  float* outCtx = (float*)d_out;                       // (8,256,256)
  float* outW   = outCtx + (size_t)B*TD*DE;            // (8,256,512)
  float* encE   = (float*)d_ws;                        // 4 MB
  float* decE   = encE + (size_t)B*DE*TE;              // 2 MB

  const bool use_dwt = ws_size >= (size_t)(B*DE*TE + B*TD*DE)*sizeof(float);

  hipLaunchKernelGGL(prep_kernel, dim3(use_dwt ? 1024 : 512), dim3(256), 0,
                     stream, enc, Wenc, dec, Wdec, encE, decE);
  if (use_dwt){
    hipLaunchKernelGGL((attn_kernel<true>), dim3(1024), dim3(512), 0, stream,
                       enc, dec, Wdec, v, encE, decE, outCtx, outW);
  } else {
    hipLaunchKernelGGL((attn_kernel<false>), dim3(1024), dim3(512), 0, stream,
                       enc, dec, Wdec, v, encE, decE, outCtx, outW);
  }
}